// Round 6
// baseline (1261.330 us; speedup 1.0000x reference)
//
#include <hip/hip_runtime.h>

#define N_NODES 50000
#define N_EDGES 600000
#define F_NODE 128
#define F_EDGE 32
#define MSG 32
#define NPB 64          // nodes per fused block
#define QBLOCKS ((N_NODES + NPB - 1) / NPB)        // 782
#define CBLOCKS ((N_EDGES + 255) / 256)            // 2344

// bf16 helpers (RNE pack)
__device__ __forceinline__ unsigned short f2bf(float f) {
    union { float f; unsigned int u; } v; v.f = f;
    unsigned int r = v.u + 0x7fffu + ((v.u >> 16) & 1u);
    return (unsigned short)(r >> 16);
}
__device__ __forceinline__ float bf2f(unsigned short h) {
    union { unsigned int u; float f; } v; v.u = ((unsigned int)h) << 16;
    return v.f;
}

// ---------------------------------------------------------------------------
// Standalone degree histogram (fallback path). Clamped bin.
// ---------------------------------------------------------------------------
__global__ void count_kernel(const int* __restrict__ idx, int* __restrict__ deg) {
    int e = blockIdx.x * 256 + threadIdx.x;
    if (e < N_EDGES) {
        int n = idx[e];
        if ((unsigned)n < (unsigned)N_NODES) atomicAdd(&deg[n], 1);
    }
}

// ---------------------------------------------------------------------------
// Full path: blocks [0,QBLOCKS) compute Q[n] = nf[n] @ We[128:256] -> bf16;
// blocks [QBLOCKS, QBLOCKS+CBLOCKS) do the degree histogram.
// ---------------------------------------------------------------------------
__global__ __launch_bounds__(256)
void qcount_kernel(const float* __restrict__ nf,
                   const float* __restrict__ We,     // [288][32]
                   const int* __restrict__ idx,      // [2][E]
                   unsigned short* __restrict__ Q,   // [N][32] bf16
                   int* __restrict__ deg)
{
    if (blockIdx.x >= QBLOCKS) {
        int e = (blockIdx.x - QBLOCKS) * 256 + threadIdx.x;
        if (e < N_EDGES) {
            int n = idx[e];
            if ((unsigned)n < (unsigned)N_NODES) atomicAdd(&deg[n], 1);
        }
        return;
    }
    __shared__ float sInT[32 * 64];   // nf^T chunk [k][node]
    __shared__ float sWeC[32 * 32];   // We chunk [k][col]

    const int tid = threadIdx.x;
    const int n0b = blockIdx.x * NPB;
    const int ng = tid & 31;          // nodes 2ng, 2ng+1
    const int og = tid >> 5;          // cols og*4 .. +3

    float accp[2][4];
#pragma unroll
    for (int i = 0; i < 2; ++i)
#pragma unroll
        for (int j = 0; j < 4; ++j) accp[i][j] = 0.f;

    for (int kc = 0; kc < 4; ++kc) {
        __syncthreads();
        ((float4*)sWeC)[tid] = ((const float4*)(We + (128 + kc * 32) * MSG))[tid];
        {
            int nl = tid >> 2, q = tid & 3;
            int n = n0b + nl; if (n >= N_NODES) n = N_NODES - 1;
            const float4* src4 = (const float4*)(nf + (size_t)n * F_NODE + kc * 32);
#pragma unroll
            for (int h = 0; h < 2; ++h) {
                float4 v = src4[q * 2 + h];
                int kl = q * 8 + h * 4;
                sInT[(kl + 0) * 64 + nl] = v.x;
                sInT[(kl + 1) * 64 + nl] = v.y;
                sInT[(kl + 2) * 64 + nl] = v.z;
                sInT[(kl + 3) * 64 + nl] = v.w;
            }
        }
        __syncthreads();
#pragma unroll
        for (int k = 0; k < 32; ++k) {
            float2 m = *(const float2*)&sInT[k * 64 + 2 * ng];
            float4 w = *(const float4*)&sWeC[k * 32 + og * 4];
            accp[0][0] += m.x * w.x; accp[0][1] += m.x * w.y;
            accp[0][2] += m.x * w.z; accp[0][3] += m.x * w.w;
            accp[1][0] += m.y * w.x; accp[1][1] += m.y * w.y;
            accp[1][2] += m.y * w.z; accp[1][3] += m.y * w.w;
        }
    }
#pragma unroll
    for (int i = 0; i < 2; ++i) {
        int n = n0b + 2 * ng + i;
        if (n < N_NODES) {
            ushort4 o;
            o.x = f2bf(accp[i][0]); o.y = f2bf(accp[i][1]);
            o.z = f2bf(accp[i][2]); o.w = f2bf(accp[i][3]);
            *(ushort4*)(Q + (size_t)n * MSG + og * 4) = o;
        }
    }
}

// ---------------------------------------------------------------------------
// CSR pass 2: in-place exclusive scan (deg -> start offsets), 1 block x 1024.
// ---------------------------------------------------------------------------
__global__ __launch_bounds__(1024)
void scan_kernel(int* __restrict__ deg_cursor) {
    __shared__ int part[1024];
    const int t = threadIdx.x;
    const int CH = (N_NODES + 1023) / 1024;   // 49
    int lo = t * CH; if (lo > N_NODES) lo = N_NODES;
    int hi = lo + CH; if (hi > N_NODES) hi = N_NODES;
    int s = 0;
    for (int i = lo; i < hi; ++i) s += deg_cursor[i];
    part[t] = s;
    __syncthreads();
    for (int d = 1; d < 1024; d <<= 1) {
        int v = (t >= d) ? part[t - d] : 0;
        __syncthreads();
        part[t] += v;
        __syncthreads();
    }
    int run = (t > 0) ? part[t - 1] : 0;
    for (int i = lo; i < hi; ++i) {
        int d = deg_cursor[i];
        deg_cursor[i] = run;
        run += d;
    }
}

// ---------------------------------------------------------------------------
// CSR pass 3: scatter edge ids into destination-sorted order. Clamped.
// Afterwards cursor[n] == end offset of node n.
// ---------------------------------------------------------------------------
__global__ void scatter_kernel(const int* __restrict__ idx, int* __restrict__ cursor,
                               int* __restrict__ perm) {
    int e = blockIdx.x * 256 + threadIdx.x;
    if (e < N_EDGES) {
        int n = idx[e];
        if ((unsigned)n >= (unsigned)N_NODES) n = 0;
        int p = atomicAdd(&cursor[n], 1);
        if ((unsigned)p < (unsigned)N_EDGES) perm[p] = e;
    }
}

// ---------------------------------------------------------------------------
// FULL-PATH fused kernel (Q decomposition). One block = 64 nodes + all their
// incoming edges. Phase 0: P0[n]=nf[n]@We[0:128]+be -> LDS bf16. Phase 1: per
// 256-edge chunk stage ef^T only; K=32 GEMM; epilogue adds P0[n0]+Q[n1],
// relu, LDS-atomic accumulate. Phase 2: node GEMM from LDS.
// All data-dependent addresses clamped: bad data -> wrong output, NOT a fault.
// ---------------------------------------------------------------------------
__global__ __launch_bounds__(256, 3)
void fused_q_kernel(const float* __restrict__ nf,
                    const int* __restrict__ idx,      // [2][E]
                    const float* __restrict__ ef,     // [E][32]
                    const float* __restrict__ We,     // [288][32]
                    const float* __restrict__ be,     // [32]
                    const float* __restrict__ Wn,     // [160][128]
                    const float* __restrict__ bn,     // [128]
                    const int* __restrict__ perm,     // [E] sorted edge ids
                    const int* __restrict__ cursor,   // [N] end offsets
                    const unsigned short* __restrict__ Q,  // [N][32] bf16
                    float* __restrict__ out)          // [N][128]
{
    __shared__ float sBuf[32 * 256];          // ef^T chunk; ph0/ph2: sInT+sWn
    __shared__ float sWeC[32 * 32];           // We K-chunk
    __shared__ float sMsgAcc[NPB * 33];
    __shared__ unsigned short sP0h[NPB * 36]; // bf16, stride 36 (8B-align)
    __shared__ int sN1[256];
    __shared__ int sLn[256];

    const int tid = threadIdx.x;
    const int n0b = blockIdx.x * NPB;
    const int nEnd = (n0b + NPB < N_NODES) ? (n0b + NPB) : N_NODES;

    for (int i = tid; i < NPB * 33; i += 256) sMsgAcc[i] = 0.f;

    int rs = (n0b == 0) ? 0 : cursor[n0b - 1];
    int re = cursor[nEnd - 1];
    if (rs < 0) rs = 0;
    if (re > N_EDGES) re = N_EDGES;
    if (rs > re) rs = re;

    float* sInT = sBuf;          // [32][64]
    float* sWn  = sBuf + 2048;   // [32][128]

    // ================= Phase 0: P0 = nf@We_top + be -> sP0h =================
    {
        const int ng = tid & 31, og0 = tid >> 5;
        float accp[2][4];
#pragma unroll
        for (int i = 0; i < 2; ++i)
#pragma unroll
            for (int j = 0; j < 4; ++j) accp[i][j] = 0.f;

        for (int kc = 0; kc < 4; ++kc) {
            __syncthreads();
            ((float4*)sWeC)[tid] = ((const float4*)(We + kc * 32 * MSG))[tid];
            {
                int nl = tid >> 2, q = tid & 3;
                int n = n0b + nl; if (n >= N_NODES) n = N_NODES - 1;
                const float4* src4 = (const float4*)(nf + (size_t)n * F_NODE + kc * 32);
#pragma unroll
                for (int h = 0; h < 2; ++h) {
                    float4 v = src4[q * 2 + h];
                    int kl = q * 8 + h * 4;
                    sInT[(kl + 0) * 64 + nl] = v.x;
                    sInT[(kl + 1) * 64 + nl] = v.y;
                    sInT[(kl + 2) * 64 + nl] = v.z;
                    sInT[(kl + 3) * 64 + nl] = v.w;
                }
            }
            __syncthreads();
#pragma unroll
            for (int k = 0; k < 32; ++k) {
                float2 m = *(const float2*)&sInT[k * 64 + 2 * ng];
                float4 w = *(const float4*)&sWeC[k * 32 + og0 * 4];
                accp[0][0] += m.x * w.x; accp[0][1] += m.x * w.y;
                accp[0][2] += m.x * w.z; accp[0][3] += m.x * w.w;
                accp[1][0] += m.y * w.x; accp[1][1] += m.y * w.y;
                accp[1][2] += m.y * w.z; accp[1][3] += m.y * w.w;
            }
        }
#pragma unroll
        for (int i = 0; i < 2; ++i)
#pragma unroll
            for (int j = 0; j < 4; ++j)
                sP0h[(2 * ng + i) * 36 + og0 * 4 + j] =
                    f2bf(accp[i][j] + be[og0 * 4 + j]);
    }

    // ================= Phase 1: edge chunks =================
    __syncthreads();   // phase-0 reads of sWeC done; sP0h written
    ((float4*)sWeC)[tid] = ((const float4*)(We + 256 * MSG))[tid];  // We_bot

    const int eg = tid & 63;   // edges 4*eg..+3
    const int og = tid >> 6;   // cols og*8..+7 (wave-uniform)

    for (int cs = rs; cs < re; cs += 256) {
        __syncthreads();   // prev chunk compute/epilogue done; We_bot staged
        {
            int e = cs + tid;
            int pe = 0, ln = -1, n1 = 0;
            if (e < re) {
                pe = perm[e];
                if ((unsigned)pe >= (unsigned)N_EDGES) pe = 0;   // poison guard
                ln = idx[pe] - n0b;
                if (ln < 0 || ln >= NPB) ln = -1;                // poison guard
                n1 = idx[N_EDGES + pe];
                if ((unsigned)n1 >= (unsigned)N_NODES) n1 = 0;   // poison guard
            }
            sLn[tid] = ln; sN1[tid] = n1;
            const float4* ef4 = (const float4*)(ef + (size_t)pe * F_EDGE);
#pragma unroll
            for (int q = 0; q < 8; ++q) {
                float4 v = ef4[q];
                sBuf[(q * 4 + 0) * 256 + tid] = v.x;
                sBuf[(q * 4 + 1) * 256 + tid] = v.y;
                sBuf[(q * 4 + 2) * 256 + tid] = v.z;
                sBuf[(q * 4 + 3) * 256 + tid] = v.w;
            }
        }
        __syncthreads();

        float acc[4][8];
#pragma unroll
        for (int i = 0; i < 4; ++i)
#pragma unroll
            for (int j = 0; j < 8; ++j) acc[i][j] = 0.f;

        const float* weB = sWeC + og * 8;
#pragma unroll
        for (int k = 0; k < 32; ++k) {
            float4 m = *(const float4*)&sBuf[k * 256 + 4 * eg];
            float4 w0 = *(const float4*)&weB[k * 32];
            float4 w1 = *(const float4*)&weB[k * 32 + 4];
            float ma[4] = { m.x, m.y, m.z, m.w };
            float wv[8] = { w0.x, w0.y, w0.z, w0.w, w1.x, w1.y, w1.z, w1.w };
#pragma unroll
            for (int i = 0; i < 4; ++i)
#pragma unroll
                for (int j = 0; j < 8; ++j) acc[i][j] += ma[i] * wv[j];
        }

        // epilogue: gather Q rows first (ILP), then P0 + relu + LDS atomics
        int lns[4]; ushort4 qa[4], qb[4];
#pragma unroll
        for (int i = 0; i < 4; ++i) {
            lns[i] = sLn[4 * eg + i];
            int n1 = sN1[4 * eg + i];
            const unsigned short* qp = Q + (size_t)n1 * MSG + og * 8;
            qa[i] = *(const ushort4*)qp;
            qb[i] = *(const ushort4*)(qp + 4);
        }
#pragma unroll
        for (int i = 0; i < 4; ++i) {
            int ln = lns[i];
            if (ln < 0) continue;
            ushort4 pa = *(const ushort4*)&sP0h[ln * 36 + og * 8];
            ushort4 pb = *(const ushort4*)&sP0h[ln * 36 + og * 8 + 4];
            float p0[8] = { bf2f(pa.x), bf2f(pa.y), bf2f(pa.z), bf2f(pa.w),
                            bf2f(pb.x), bf2f(pb.y), bf2f(pb.z), bf2f(pb.w) };
            float qf[8] = { bf2f(qa[i].x), bf2f(qa[i].y), bf2f(qa[i].z), bf2f(qa[i].w),
                            bf2f(qb[i].x), bf2f(qb[i].y), bf2f(qb[i].z), bf2f(qb[i].w) };
            float* row = &sMsgAcc[ln * 33 + og * 8];
#pragma unroll
            for (int j = 0; j < 8; ++j) {
                float v = acc[i][j] + p0[j] + qf[j];
                v = v > 0.f ? v : 0.f;
                atomicAdd(&row[j], v);
            }
        }
    }

    // ================= Phase 2: node GEMM =================
    const int ng  = tid & 31;
    const int og2 = tid >> 5;

    float acc2[2][16];
#pragma unroll
    for (int i = 0; i < 2; ++i)
#pragma unroll
        for (int j = 0; j < 16; ++j) acc2[i][j] = 0.f;

    for (int kc = 0; kc < 5; ++kc) {
        __syncthreads();
        {
            const float4* w4 = (const float4*)(Wn + (size_t)kc * 32 * 128);
            float4* s4 = (float4*)sWn;
#pragma unroll
            for (int i = 0; i < 4; ++i) s4[tid + 256 * i] = w4[tid + 256 * i];
        }
        {
            int nl = tid >> 2, q = tid & 3;
            if (kc < 4) {
                int n = n0b + nl; if (n >= N_NODES) n = N_NODES - 1;
                const float4* src4 = (const float4*)(nf + (size_t)n * F_NODE + kc * 32);
#pragma unroll
                for (int h = 0; h < 2; ++h) {
                    float4 v = src4[q * 2 + h];
                    int kl = q * 8 + h * 4;
                    sInT[(kl + 0) * 64 + nl] = v.x;
                    sInT[(kl + 1) * 64 + nl] = v.y;
                    sInT[(kl + 2) * 64 + nl] = v.z;
                    sInT[(kl + 3) * 64 + nl] = v.w;
                }
            } else {
#pragma unroll
                for (int h = 0; h < 8; ++h) {
                    int kl = q * 8 + h;
                    sInT[kl * 64 + nl] = sMsgAcc[nl * 33 + kl];
                }
            }
        }
        __syncthreads();

#pragma unroll
        for (int k = 0; k < 32; ++k) {
            float2 m = *(const float2*)&sInT[k * 64 + 2 * ng];
            const float* wr = &sWn[k * 128 + og2 * 16];
            float4 w0 = *(const float4*)&wr[0];
            float4 w1 = *(const float4*)&wr[4];
            float4 w2 = *(const float4*)&wr[8];
            float4 w3 = *(const float4*)&wr[12];
            float ma[2] = { m.x, m.y };
            float wv[16] = { w0.x,w0.y,w0.z,w0.w, w1.x,w1.y,w1.z,w1.w,
                             w2.x,w2.y,w2.z,w2.w, w3.x,w3.y,w3.z,w3.w };
#pragma unroll
            for (int i = 0; i < 2; ++i)
#pragma unroll
                for (int j = 0; j < 16; ++j) acc2[i][j] += ma[i] * wv[j];
        }
    }

    float nbias[16];
#pragma unroll
    for (int j = 0; j < 16; ++j) nbias[j] = bn[og2 * 16 + j];

#pragma unroll
    for (int i = 0; i < 2; ++i) {
        int n = n0b + 2 * ng + i;
        if (n < N_NODES) {
            float* dst = out + (size_t)n * F_NODE + og2 * 16;
#pragma unroll
            for (int j = 0; j < 16; j += 4) {
                float4 v;
                v.x = fmaxf(acc2[i][j + 0] + nbias[j + 0], 0.f);
                v.y = fmaxf(acc2[i][j + 1] + nbias[j + 1], 0.f);
                v.z = fmaxf(acc2[i][j + 2] + nbias[j + 2], 0.f);
                v.w = fmaxf(acc2[i][j + 3] + nbias[j + 3], 0.f);
                *(float4*)(dst + j) = v;
            }
        }
    }
}

// ---------------------------------------------------------------------------
// FALLBACK fused kernel: round-4 structure (proven PASS @ 472us), full edge
// GEMM (9 K-chunks), no Q. Used when ws_size < full-path requirement.
// ---------------------------------------------------------------------------
__global__ __launch_bounds__(256, 3)
void fused_noq_kernel(const float* __restrict__ nf,
                      const int* __restrict__ idx,
                      const float* __restrict__ ef,
                      const float* __restrict__ We,
                      const float* __restrict__ be,
                      const float* __restrict__ Wn,
                      const float* __restrict__ bn,
                      const int* __restrict__ perm,
                      const int* __restrict__ cursor,
                      float* __restrict__ out)
{
    __shared__ float sBuf[32 * 256];
    __shared__ float sWeC[32 * 32];
    __shared__ float sMsgAcc[NPB * 33];
    __shared__ int sEid[256];
    __shared__ int sLn[256];
    __shared__ int sN1[256];

    const int tid = threadIdx.x;
    const int n0b = blockIdx.x * NPB;
    const int nEnd = (n0b + NPB < N_NODES) ? (n0b + NPB) : N_NODES;

    for (int i = tid; i < NPB * 33; i += 256) sMsgAcc[i] = 0.f;

    int rs = (n0b == 0) ? 0 : cursor[n0b - 1];
    int re = cursor[nEnd - 1];
    if (rs < 0) rs = 0;
    if (re > N_EDGES) re = N_EDGES;
    if (rs > re) rs = re;

    const int eg = tid & 63;
    const int og = tid >> 6;

    float ebias[8];
#pragma unroll
    for (int j = 0; j < 8; ++j) ebias[j] = be[og * 8 + j];

    for (int cs = rs; cs < re; cs += 256) {
        __syncthreads();
        {
            int e = cs + tid;
            int pe = 0, ln = -1, n1 = 0;
            if (e < re) {
                pe = perm[e];
                if ((unsigned)pe >= (unsigned)N_EDGES) pe = 0;
                ln = idx[pe] - n0b;
                if (ln < 0 || ln >= NPB) ln = -1;
                n1 = idx[N_EDGES + pe];
                if ((unsigned)n1 >= (unsigned)N_NODES) n1 = 0;
            }
            sEid[tid] = pe; sLn[tid] = ln; sN1[tid] = n1;
        }

        float acc[4][8];
#pragma unroll
        for (int i = 0; i < 4; ++i)
#pragma unroll
            for (int j = 0; j < 8; ++j) acc[i][j] = 0.f;

        for (int kc = 0; kc < 9; ++kc) {
            __syncthreads();
            ((float4*)sWeC)[tid] = ((const float4*)(We + kc * 32 * MSG))[tid];
            {
                const float* src;
                if (kc < 4) {
                    int ln = sLn[tid]; if (ln < 0) ln = 0;
                    int n = n0b + ln; if (n >= N_NODES) n = N_NODES - 1;
                    src = nf + (size_t)n * F_NODE + kc * 32;
                } else if (kc < 8) {
                    src = nf + (size_t)sN1[tid] * F_NODE + (kc - 4) * 32;
                } else {
                    src = ef + (size_t)sEid[tid] * F_EDGE;
                }
                const float4* src4 = (const float4*)src;
#pragma unroll
                for (int q = 0; q < 8; ++q) {
                    float4 v = src4[q];
                    sBuf[(q * 4 + 0) * 256 + tid] = v.x;
                    sBuf[(q * 4 + 1) * 256 + tid] = v.y;
                    sBuf[(q * 4 + 2) * 256 + tid] = v.z;
                    sBuf[(q * 4 + 3) * 256 + tid] = v.w;
                }
            }
            __syncthreads();

            const float* weB = sWeC + og * 8;
#pragma unroll
            for (int k = 0; k < 32; ++k) {
                float4 m = *(const float4*)&sBuf[k * 256 + 4 * eg];
                float4 w0 = *(const float4*)&weB[k * 32];
                float4 w1 = *(const float4*)&weB[k * 32 + 4];
                float ma[4] = { m.x, m.y, m.z, m.w };
                float wv[8] = { w0.x, w0.y, w0.z, w0.w, w1.x, w1.y, w1.z, w1.w };
#pragma unroll
                for (int i = 0; i < 4; ++i)
#pragma unroll
                    for (int j = 0; j < 8; ++j) acc[i][j] += ma[i] * wv[j];
            }
        }

#pragma unroll
        for (int i = 0; i < 4; ++i) {
            int ln = sLn[4 * eg + i];
            if (ln >= 0) {
                float* row = &sMsgAcc[ln * 33 + og * 8];
#pragma unroll
                for (int j = 0; j < 8; ++j) {
                    float v = acc[i][j] + ebias[j];
                    v = v > 0.f ? v : 0.f;
                    atomicAdd(&row[j], v);
                }
            }
        }
    }

    float* sInT = sBuf;
    float* sWn  = sBuf + 2048;
    const int ng  = tid & 31;
    const int og2 = tid >> 5;

    float acc2[2][16];
#pragma unroll
    for (int i = 0; i < 2; ++i)
#pragma unroll
        for (int j = 0; j < 16; ++j) acc2[i][j] = 0.f;

    for (int kc = 0; kc < 5; ++kc) {
        __syncthreads();
        {
            const float4* w4 = (const float4*)(Wn + (size_t)kc * 32 * 128);
            float4* s4 = (float4*)sWn;
#pragma unroll
            for (int i = 0; i < 4; ++i) s4[tid + 256 * i] = w4[tid + 256 * i];
        }
        {
            int nl = tid >> 2, q = tid & 3;
            if (kc < 4) {
                int n = n0b + nl; if (n >= N_NODES) n = N_NODES - 1;
                const float4* src4 = (const float4*)(nf + (size_t)n * F_NODE + kc * 32);
#pragma unroll
                for (int h = 0; h < 2; ++h) {
                    float4 v = src4[q * 2 + h];
                    int kl = q * 8 + h * 4;
                    sInT[(kl + 0) * 64 + nl] = v.x;
                    sInT[(kl + 1) * 64 + nl] = v.y;
                    sInT[(kl + 2) * 64 + nl] = v.z;
                    sInT[(kl + 3) * 64 + nl] = v.w;
                }
            } else {
#pragma unroll
                for (int h = 0; h < 8; ++h) {
                    int kl = q * 8 + h;
                    sInT[kl * 64 + nl] = sMsgAcc[nl * 33 + kl];
                }
            }
        }
        __syncthreads();

#pragma unroll
        for (int k = 0; k < 32; ++k) {
            float2 m = *(const float2*)&sInT[k * 64 + 2 * ng];
            const float* wr = &sWn[k * 128 + og2 * 16];
            float4 w0 = *(const float4*)&wr[0];
            float4 w1 = *(const float4*)&wr[4];
            float4 w2 = *(const float4*)&wr[8];
            float4 w3 = *(const float4*)&wr[12];
            float ma[2] = { m.x, m.y };
            float wv[16] = { w0.x,w0.y,w0.z,w0.w, w1.x,w1.y,w1.z,w1.w,
                             w2.x,w2.y,w2.z,w2.w, w3.x,w3.y,w3.z,w3.w };
#pragma unroll
            for (int i = 0; i < 2; ++i)
#pragma unroll
                for (int j = 0; j < 16; ++j) acc2[i][j] += ma[i] * wv[j];
        }
    }

    float nbias[16];
#pragma unroll
    for (int j = 0; j < 16; ++j) nbias[j] = bn[og2 * 16 + j];

#pragma unroll
    for (int i = 0; i < 2; ++i) {
        int n = n0b + 2 * ng + i;
        if (n < N_NODES) {
            float* dst = out + (size_t)n * F_NODE + og2 * 16;
#pragma unroll
            for (int j = 0; j < 16; j += 4) {
                float4 v;
                v.x = fmaxf(acc2[i][j + 0] + nbias[j + 0], 0.f);
                v.y = fmaxf(acc2[i][j + 1] + nbias[j + 1], 0.f);
                v.z = fmaxf(acc2[i][j + 2] + nbias[j + 2], 0.f);
                v.w = fmaxf(acc2[i][j + 3] + nbias[j + 3], 0.f);
                *(float4*)(dst + j) = v;
            }
        }
    }
}

extern "C" void kernel_launch(void* const* d_in, const int* in_sizes, int n_in,
                              void* d_out, int out_size, void* d_ws, size_t ws_size,
                              hipStream_t stream) {
    const float* nf  = (const float*)d_in[0];
    const int*   idx = (const int*)d_in[1];
    const float* ef  = (const float*)d_in[2];
    const float* We  = (const float*)d_in[3];
    const float* be  = (const float*)d_in[4];
    const float* Wn  = (const float*)d_in[5];
    const float* bn  = (const float*)d_in[6];
    float* out = (float*)d_out;

    // Full path needs deg(0.2MB) + perm(2.4MB) + Q bf16(3.2MB) = 5.8MB.
    // ws_size is launch-constant, so this branch is deterministic across
    // calls (graph-capture safe). Fallback = round-4 proven 2.6MB layout.
    const size_t REQ_FULL = (size_t)N_NODES * 4 + (size_t)N_EDGES * 4
                          + (size_t)N_NODES * MSG * 2;

    int* deg_cursor = (int*)d_ws;                 // 50000 (deg -> cursor)
    int* perm       = deg_cursor + N_NODES;       // 600000

    hipMemsetAsync(deg_cursor, 0, (size_t)N_NODES * sizeof(int), stream);

    if (ws_size >= REQ_FULL) {
        unsigned short* Q = (unsigned short*)(perm + N_EDGES);  // [N][32] bf16
        qcount_kernel<<<QBLOCKS + CBLOCKS, 256, 0, stream>>>(nf, We, idx, Q, deg_cursor);
        scan_kernel<<<1, 1024, 0, stream>>>(deg_cursor);
        scatter_kernel<<<CBLOCKS, 256, 0, stream>>>(idx, deg_cursor, perm);
        fused_q_kernel<<<QBLOCKS, 256, 0, stream>>>(
            nf, idx, ef, We, be, Wn, bn, perm, deg_cursor, Q, out);
    } else {
        count_kernel<<<CBLOCKS, 256, 0, stream>>>(idx, deg_cursor);
        scan_kernel<<<1, 1024, 0, stream>>>(deg_cursor);
        scatter_kernel<<<CBLOCKS, 256, 0, stream>>>(idx, deg_cursor, perm);
        fused_noq_kernel<<<QBLOCKS, 256, 0, stream>>>(
            nf, idx, ef, We, be, Wn, bn, perm, deg_cursor, out);
    }
}